// Round 1
// baseline (2480.368 us; speedup 1.0000x reference)
//
#include <hip/hip_runtime.h>
#include <math.h>

#define F_DIM 128
#define D_LAT 64
#define H_DIM 128

// ---------------- encoder: mu/logvar/z + KL ----------------
__global__ __launch_bounds__(256) void enc_kernel(
    const float* __restrict__ x, const float* __restrict__ eps,
    const float* __restrict__ Wmu, const float* __restrict__ bmu,
    const float* __restrict__ Wlv, const float* __restrict__ blv,
    float* __restrict__ z, float* __restrict__ accum, int nNodes)
{
    __shared__ float Wmu_s[F_DIM * D_LAT];
    __shared__ float Wlv_s[F_DIM * D_LAT];
    __shared__ float bmu_s[D_LAT], blv_s[D_LAT];
    for (int i = threadIdx.x; i < F_DIM * D_LAT; i += 256) {
        Wmu_s[i] = Wmu[i];
        Wlv_s[i] = Wlv[i];
    }
    if (threadIdx.x < D_LAT) {
        bmu_s[threadIdx.x] = bmu[threadIdx.x];
        blv_s[threadIdx.x] = blv[threadIdx.x];
    }
    __syncthreads();

    const int lane = threadIdx.x & 63;
    const int wid  = (blockIdx.x * blockDim.x + threadIdx.x) >> 6;
    const int nw   = (gridDim.x * blockDim.x) >> 6;

    float klacc = 0.f;
    for (int n = wid; n < nNodes; n += nw) {
        const float x0 = x[n * F_DIM + lane];
        const float x1 = x[n * F_DIM + 64 + lane];
        float amu = bmu_s[lane], alv = blv_s[lane];
#pragma unroll
        for (int k = 0; k < 64; ++k) {
            const float xk = __shfl(x0, k);
            amu = fmaf(xk, Wmu_s[k * D_LAT + lane], amu);
            alv = fmaf(xk, Wlv_s[k * D_LAT + lane], alv);
        }
#pragma unroll
        for (int k = 0; k < 64; ++k) {
            const float xk = __shfl(x1, k);
            amu = fmaf(xk, Wmu_s[(64 + k) * D_LAT + lane], amu);
            alv = fmaf(xk, Wlv_s[(64 + k) * D_LAT + lane], alv);
        }
        const float e = eps[n * D_LAT + lane];
        z[n * D_LAT + lane] = fmaf(e, expf(0.5f * alv), amu);
        klacc += amu * amu + expf(alv) - 1.0f - alv;
    }
    // wave reduce (all 64 lanes)
    for (int off = 32; off; off >>= 1) klacc += __shfl_xor(klacc, off);
    if (lane == 0) atomicAdd(&accum[1], 0.5f * klacc);
}

// ---------------- edge scorer: pair MLP + log-sigmoid ----------------
__global__ __launch_bounds__(256) void edge_kernel(
    const float* __restrict__ z,
    const int* __restrict__ eidx, const int* __restrict__ nidx,
    const float* __restrict__ W1, const float* __restrict__ b1,
    const float* __restrict__ W2, const float* __restrict__ b2,
    float* __restrict__ accum, int E)
{
    __shared__ float W1_s[D_LAT * H_DIM];
    __shared__ float b1_s[H_DIM];
    __shared__ float W2_s[H_DIM];
    for (int i = threadIdx.x; i < D_LAT * H_DIM; i += 256) W1_s[i] = W1[i];
    if (threadIdx.x < H_DIM) {
        b1_s[threadIdx.x] = b1[threadIdx.x];
        W2_s[threadIdx.x] = W2[threadIdx.x];
    }
    __syncthreads();
    const float b2v = b2[0];

    const int lane = threadIdx.x & 63;
    const int wid  = (blockIdx.x * blockDim.x + threadIdx.x) >> 6;
    const int nw   = (gridDim.x * blockDim.x) >> 6;
    const int total = 2 * E;

    float lpacc = 0.f;
    for (int p = wid; p < total; p += nw) {
        const bool pos = p < E;
        const int  pp  = pos ? p : p - E;
        const int* __restrict__ idx = pos ? eidx : nidx;
        const int u = idx[pp];
        const int v = idx[E + pp];
        // lane d holds p_d = z[u][d] * z[v][d]
        const float pd = z[u * D_LAT + lane] * z[v * D_LAT + lane];
        // lane l computes h[l] and h[l+64]
        float a0 = b1_s[lane], a1 = b1_s[64 + lane];
#pragma unroll
        for (int d = 0; d < 64; ++d) {
            const float pdd = __shfl(pd, d);
            a0 = fmaf(pdd, W1_s[d * H_DIM + lane], a0);
            a1 = fmaf(pdd, W1_s[d * H_DIM + 64 + lane], a1);
        }
        float t = fmaxf(a0, 0.f) * W2_s[lane] + fmaxf(a1, 0.f) * W2_s[64 + lane];
        for (int off = 32; off; off >>= 1) t += __shfl_xor(t, off);
        const float logit = t + b2v;
        const float s = pos ? logit : -logit;
        // numerically-stable log_sigmoid
        lpacc += fminf(s, 0.f) - log1pf(expf(-fabsf(s)));
    }
    // lpacc is lane-uniform (post-butterfly) — one atomic per wave
    if (lane == 0) atomicAdd(&accum[0], lpacc);
}

// ---------------- finalize ----------------
__global__ void fin_kernel(const float* __restrict__ accum, float* __restrict__ out,
                           int nNodes, int E)
{
    const float recon = accum[0] / (float)(2 * E);
    const float kl    = accum[1] / (float)nNodes;
    out[0] = kl - recon;   // -(recon - kl)
}

extern "C" void kernel_launch(void* const* d_in, const int* in_sizes, int n_in,
                              void* d_out, int out_size, void* d_ws, size_t ws_size,
                              hipStream_t stream)
{
    const float* x    = (const float*)d_in[0];
    const float* eps  = (const float*)d_in[1];
    const float* Wmu  = (const float*)d_in[2];
    const float* bmu  = (const float*)d_in[3];
    const float* Wlv  = (const float*)d_in[4];
    const float* blv  = (const float*)d_in[5];
    const float* W1   = (const float*)d_in[6];
    const float* b1   = (const float*)d_in[7];
    const float* W2   = (const float*)d_in[8];
    const float* b2   = (const float*)d_in[9];
    const int*   eidx = (const int*)d_in[10];
    const int*   nidx = (const int*)d_in[11];

    const int nNodes = in_sizes[1] / D_LAT;   // 100000
    const int E      = in_sizes[10] / 2;      // 1000000

    float* accum = (float*)d_ws;                      // [0]=recon_sum, [1]=kl_sum
    float* z     = (float*)((char*)d_ws + 256);       // nNodes*D_LAT floats

    hipMemsetAsync(d_ws, 0, 256, stream);
    enc_kernel<<<1024, 256, 0, stream>>>(x, eps, Wmu, bmu, Wlv, blv, z, accum, nNodes);
    edge_kernel<<<2048, 256, 0, stream>>>(z, eidx, nidx, W1, b1, W2, b2, accum, E);
    fin_kernel<<<1, 1, 0, stream>>>(accum, (float*)d_out, nNodes, E);
}

// Round 2
// 654.370 us; speedup vs baseline: 3.7905x; 3.7905x over previous
//
#include <hip/hip_runtime.h>
#include <math.h>

#define F_DIM 128
#define D_LAT 64
#define H_DIM 128

typedef __attribute__((ext_vector_type(8))) short bf16x8;     // 8 bf16 in 4 VGPRs
typedef __attribute__((ext_vector_type(8))) unsigned short u16x8;
typedef __attribute__((ext_vector_type(4))) float f32x4;

__device__ __forceinline__ unsigned short f2bf(float f) {
    unsigned int u = __builtin_bit_cast(unsigned int, f);
    return (unsigned short)((u + 0x8000u) >> 16);   // round-half-up, plenty for 2% threshold
}
__device__ __forceinline__ float bf2f(unsigned short s) {
    unsigned int u = ((unsigned int)s) << 16;
    return __builtin_bit_cast(float, u);
}

// ---------------- encoder: mu/logvar/z (bf16 out) + KL ----------------
__global__ __launch_bounds__(256) void enc_kernel(
    const float* __restrict__ x, const float* __restrict__ eps,
    const float* __restrict__ Wmu, const float* __restrict__ bmu,
    const float* __restrict__ Wlv, const float* __restrict__ blv,
    unsigned short* __restrict__ zb, float* __restrict__ accum, int nNodes)
{
    __shared__ float Wmu_s[F_DIM * D_LAT];
    __shared__ float Wlv_s[F_DIM * D_LAT];
    __shared__ float bmu_s[D_LAT], blv_s[D_LAT];
    for (int i = threadIdx.x; i < F_DIM * D_LAT; i += 256) {
        Wmu_s[i] = Wmu[i];
        Wlv_s[i] = Wlv[i];
    }
    if (threadIdx.x < D_LAT) {
        bmu_s[threadIdx.x] = bmu[threadIdx.x];
        blv_s[threadIdx.x] = blv[threadIdx.x];
    }
    __syncthreads();

    const int lane = threadIdx.x & 63;
    const int wid  = (blockIdx.x * blockDim.x + threadIdx.x) >> 6;
    const int nw   = (gridDim.x * blockDim.x) >> 6;

    float klacc = 0.f;
    for (int n = wid; n < nNodes; n += nw) {
        const float x0 = x[n * F_DIM + lane];
        const float x1 = x[n * F_DIM + 64 + lane];
        float amu = bmu_s[lane], alv = blv_s[lane];
#pragma unroll
        for (int k = 0; k < 64; ++k) {
            const float xk = __shfl(x0, k);
            amu = fmaf(xk, Wmu_s[k * D_LAT + lane], amu);
            alv = fmaf(xk, Wlv_s[k * D_LAT + lane], alv);
        }
#pragma unroll
        for (int k = 0; k < 64; ++k) {
            const float xk = __shfl(x1, k);
            amu = fmaf(xk, Wmu_s[(64 + k) * D_LAT + lane], amu);
            alv = fmaf(xk, Wlv_s[(64 + k) * D_LAT + lane], alv);
        }
        const float e = eps[n * D_LAT + lane];
        zb[(size_t)n * D_LAT + lane] = f2bf(fmaf(e, expf(0.5f * alv), amu));
        klacc += amu * amu + expf(alv) - 1.0f - alv;
    }
    for (int off = 32; off; off >>= 1) klacc += __shfl_xor(klacc, off);
    if (lane == 0) atomicAdd(&accum[1], 0.5f * klacc);
}

// ---------------- edge scorer: 16 pairs/wave via bf16 MFMA ----------------
// A = P[16 pairs x 64 dims], B = W1[64 x 128] (8 col-tiles x 2 k-steps).
// mfma_f32_16x16x32_bf16 layouts (m89-verified):
//   A: lane l, elem j -> A[l&15][(l>>4)*8 + j]
//   B: lane l, elem j -> B[(l>>4)*8 + j][l&15]
//   D: lane l, reg r  -> D[(l>>4)*4 + r][l&15]
__global__ __launch_bounds__(256) void edge_mfma_kernel(
    const unsigned short* __restrict__ zb,
    const int* __restrict__ eidx, const int* __restrict__ nidx,
    const float* __restrict__ W1, const float* __restrict__ b1,
    const float* __restrict__ W2, const float* __restrict__ b2,
    float* __restrict__ accum, int E)
{
    const int lane = threadIdx.x & 63;
    const int li   = lane & 15;   // pair-in-block (A row) / hidden col
    const int gi   = lane >> 4;   // k-group

    // loop-invariant W1 fragments in registers: 16 frags x 4 VGPR = 64 VGPR
    bf16x8 w1f[8][2];
#pragma unroll
    for (int t = 0; t < 8; ++t)
#pragma unroll
        for (int s = 0; s < 2; ++s)
#pragma unroll
            for (int j = 0; j < 8; ++j)
                w1f[t][s][j] = (short)f2bf(W1[(32 * s + gi * 8 + j) * H_DIM + 16 * t + li]);
    float b1r[8], w2r[8];
#pragma unroll
    for (int t = 0; t < 8; ++t) {
        b1r[t] = b1[16 * t + li];
        w2r[t] = W2[16 * t + li];
    }
    const float b2v = b2[0];

    const int wid = (blockIdx.x * blockDim.x + threadIdx.x) >> 6;
    const int nw  = (gridDim.x * blockDim.x) >> 6;
    const int NBpos = E >> 4;        // E divisible by 16 (E = 1e6)
    const int NB    = NBpos << 1;

    float lp = 0.f;
    for (int pb = wid; pb < NB; pb += nw) {
        const bool pos = pb < NBpos;
        const int pbase = (pos ? pb : pb - NBpos) << 4;
        const int* __restrict__ idx = pos ? eidx : nidx;
        const int u = idx[pbase + li];
        const int v = idx[E + pbase + li];

        const unsigned short* zu = zb + (size_t)u * D_LAT + gi * 8;
        const unsigned short* zv = zb + (size_t)v * D_LAT + gi * 8;
        const u16x8 a0 = *(const u16x8*)(zu);
        const u16x8 a1 = *(const u16x8*)(zu + 32);
        const u16x8 c0 = *(const u16x8*)(zv);
        const u16x8 c1 = *(const u16x8*)(zv + 32);

        bf16x8 pa0, pa1;
#pragma unroll
        for (int j = 0; j < 8; ++j) {
            pa0[j] = (short)f2bf(bf2f(a0[j]) * bf2f(c0[j]));
            pa1[j] = (short)f2bf(bf2f(a1[j]) * bf2f(c1[j]));
        }

        f32x4 acc[8];
#pragma unroll
        for (int t = 0; t < 8; ++t) acc[t] = (f32x4){0.f, 0.f, 0.f, 0.f};
#pragma unroll
        for (int t = 0; t < 8; ++t) {
            acc[t] = __builtin_amdgcn_mfma_f32_16x16x32_bf16(pa0, w1f[t][0], acc[t], 0, 0, 0);
            acc[t] = __builtin_amdgcn_mfma_f32_16x16x32_bf16(pa1, w1f[t][1], acc[t], 0, 0, 0);
        }

        // per-pair logit: sum over 128 hidden of relu(h)*W2  (cols split across 16 lanes x 8 tiles)
        float t0 = 0.f, t1 = 0.f, t2 = 0.f, t3 = 0.f;
#pragma unroll
        for (int t = 0; t < 8; ++t) {
            t0 += fmaxf(acc[t][0] + b1r[t], 0.f) * w2r[t];
            t1 += fmaxf(acc[t][1] + b1r[t], 0.f) * w2r[t];
            t2 += fmaxf(acc[t][2] + b1r[t], 0.f) * w2r[t];
            t3 += fmaxf(acc[t][3] + b1r[t], 0.f) * w2r[t];
        }
#pragma unroll
        for (int off = 1; off < 16; off <<= 1) {
            t0 += __shfl_xor(t0, off);
            t1 += __shfl_xor(t1, off);
            t2 += __shfl_xor(t2, off);
            t3 += __shfl_xor(t3, off);
        }
        // lane group gi holds logits of pairs pbase + gi*4 + {0,1,2,3}, replicated x16
        const float sg = pos ? 1.f : -1.f;
        const float l0 = sg * (t0 + b2v), l1 = sg * (t1 + b2v);
        const float l2 = sg * (t2 + b2v), l3 = sg * (t3 + b2v);
        lp += fminf(l0, 0.f) - __logf(1.f + __expf(-fabsf(l0)));
        lp += fminf(l1, 0.f) - __logf(1.f + __expf(-fabsf(l1)));
        lp += fminf(l2, 0.f) - __logf(1.f + __expf(-fabsf(l2)));
        lp += fminf(l3, 0.f) - __logf(1.f + __expf(-fabsf(l3)));
    }
    // each group's contribution replicated x16 -> full butterfly gives 16 * true sum
    for (int off = 32; off; off >>= 1) lp += __shfl_xor(lp, off);
    if (lane == 0) atomicAdd(&accum[0], lp * 0.0625f);
}

// ---------------- finalize ----------------
__global__ void fin_kernel(const float* __restrict__ accum, float* __restrict__ out,
                           int nNodes, int E)
{
    const float recon = accum[0] / (float)(2 * E);
    const float kl    = accum[1] / (float)nNodes;
    out[0] = kl - recon;   // -(recon - kl)
}

extern "C" void kernel_launch(void* const* d_in, const int* in_sizes, int n_in,
                              void* d_out, int out_size, void* d_ws, size_t ws_size,
                              hipStream_t stream)
{
    const float* x    = (const float*)d_in[0];
    const float* eps  = (const float*)d_in[1];
    const float* Wmu  = (const float*)d_in[2];
    const float* bmu  = (const float*)d_in[3];
    const float* Wlv  = (const float*)d_in[4];
    const float* blv  = (const float*)d_in[5];
    const float* W1   = (const float*)d_in[6];
    const float* b1   = (const float*)d_in[7];
    const float* W2   = (const float*)d_in[8];
    const float* b2   = (const float*)d_in[9];
    const int*   eidx = (const int*)d_in[10];
    const int*   nidx = (const int*)d_in[11];

    const int nNodes = in_sizes[1] / D_LAT;   // 100000
    const int E      = in_sizes[10] / 2;      // 1000000

    float* accum          = (float*)d_ws;                    // [0]=recon_sum [1]=kl_sum
    unsigned short* zbf16 = (unsigned short*)((char*)d_ws + 256);  // nNodes*64 bf16

    hipMemsetAsync(d_ws, 0, 256, stream);
    enc_kernel<<<1024, 256, 0, stream>>>(x, eps, Wmu, bmu, Wlv, blv, zbf16, accum, nNodes);
    edge_mfma_kernel<<<2048, 256, 0, stream>>>(zbf16, eidx, nidx, W1, b1, W2, b2, accum, E);
    fin_kernel<<<1, 1, 0, stream>>>(accum, (float*)d_out, nNodes, E);
}

// Round 3
// 212.510 us; speedup vs baseline: 11.6718x; 3.0792x over previous
//
#include <hip/hip_runtime.h>
#include <math.h>

#define F_DIM 128
#define D_LAT 64
#define H_DIM 128

typedef __attribute__((ext_vector_type(8))) short bf16x8;     // 8 bf16 in 4 VGPRs
typedef __attribute__((ext_vector_type(8))) unsigned short u16x8;
typedef __attribute__((ext_vector_type(4))) float f32x4;

__device__ __forceinline__ unsigned short f2bf(float f) {
    unsigned int u = __builtin_bit_cast(unsigned int, f);
    return (unsigned short)((u + 0x8000u) >> 16);
}
__device__ __forceinline__ float bf2f(unsigned short s) {
    unsigned int u = ((unsigned int)s) << 16;
    return __builtin_bit_cast(float, u);
}

// ---------------- encoder via MFMA: 16 nodes/wave ----------------
// A = x[16 nodes x 128 feat] (4 k-steps), B = [Wmu|Wlv][128 x 128] (8 col-tiles).
// mfma_f32_16x16x32_bf16 layouts (validated by R1 edge kernel, absmax 0.0):
//   A: lane l, elem j -> A[l&15][(l>>4)*8 + j]
//   B: lane l, elem j -> B[(l>>4)*8 + j][l&15]
//   D: lane l, reg r  -> D[(l>>4)*4 + r][l&15]
__global__ __launch_bounds__(256) void enc_mfma_kernel(
    const float* __restrict__ x, const float* __restrict__ eps,
    const float* __restrict__ Wmu, const float* __restrict__ bmu,
    const float* __restrict__ Wlv, const float* __restrict__ blv,
    unsigned short* __restrict__ zb, float* __restrict__ accum, int nNodes)
{
    const int lane = threadIdx.x & 63;
    const int li   = lane & 15;   // node-in-block / output col
    const int gi   = lane >> 4;   // k-group

    // register-resident weights: tiles 0..3 = Wmu cols, 4..7 = Wlv cols
    bf16x8 wf[8][4];
#pragma unroll
    for (int t = 0; t < 4; ++t)
#pragma unroll
        for (int s = 0; s < 4; ++s)
#pragma unroll
            for (int j = 0; j < 8; ++j) {
                const int k = s * 32 + gi * 8 + j;
                wf[t][s][j]     = (short)f2bf(Wmu[k * D_LAT + 16 * t + li]);
                wf[t + 4][s][j] = (short)f2bf(Wlv[k * D_LAT + 16 * t + li]);
            }
    const float bmu_r = bmu[li & 15];  // b is zeros in practice but honor it: col = 16t+li
    (void)bmu_r;
    float bmu4[4], blv4[4];
#pragma unroll
    for (int t = 0; t < 4; ++t) {
        bmu4[t] = bmu[16 * t + li];
        blv4[t] = blv[16 * t + li];
    }

    const int wid = (blockIdx.x * blockDim.x + threadIdx.x) >> 6;
    const int nw  = (gridDim.x * blockDim.x) >> 6;
    const int NB  = nNodes >> 4;   // 100000/16 = 6250

    float klacc = 0.f;
    for (int nb = wid; nb < NB; nb += nw) {
        const int nbase = nb << 4;
        const float* __restrict__ xrow = x + (size_t)(nbase + li) * F_DIM;

        bf16x8 af[4];
#pragma unroll
        for (int s = 0; s < 4; ++s) {
            const f32x4 v0 = *(const f32x4*)(xrow + s * 32 + gi * 8);
            const f32x4 v1 = *(const f32x4*)(xrow + s * 32 + gi * 8 + 4);
#pragma unroll
            for (int j = 0; j < 4; ++j) {
                af[s][j]     = (short)f2bf(v0[j]);
                af[s][j + 4] = (short)f2bf(v1[j]);
            }
        }

        f32x4 acc[8];
#pragma unroll
        for (int t = 0; t < 8; ++t) acc[t] = (f32x4){0.f, 0.f, 0.f, 0.f};
#pragma unroll
        for (int t = 0; t < 8; ++t)
#pragma unroll
            for (int s = 0; s < 4; ++s)
                acc[t] = __builtin_amdgcn_mfma_f32_16x16x32_bf16(af[s], wf[t][s], acc[t], 0, 0, 0);

        // epilogue: lane owns rows nbase+gi*4+r, cols 16t+li (mu in acc[t], lv in acc[t+4])
#pragma unroll
        for (int r = 0; r < 4; ++r) {
            const int row = nbase + gi * 4 + r;
#pragma unroll
            for (int t = 0; t < 4; ++t) {
                const float mu  = acc[t][r] + bmu4[t];
                const float lv  = acc[t + 4][r] + blv4[t];
                const float e05 = __expf(0.5f * lv);           // exp(lv) = e05*e05
                klacc += mu * mu + e05 * e05 - 1.0f - lv;
                const float zv = fmaf(eps[(size_t)row * D_LAT + 16 * t + li], e05, mu);
                zb[(size_t)row * D_LAT + 16 * t + li] = f2bf(zv);
            }
        }
    }
    for (int off = 32; off; off >>= 1) klacc += __shfl_xor(klacc, off);
    if (lane == 0) atomicAdd(&accum[1], 0.5f * klacc);
}

// ---------------- edge scorer: 16 pairs/wave via bf16 MFMA (unchanged) ----------------
__global__ __launch_bounds__(256) void edge_mfma_kernel(
    const unsigned short* __restrict__ zb,
    const int* __restrict__ eidx, const int* __restrict__ nidx,
    const float* __restrict__ W1, const float* __restrict__ b1,
    const float* __restrict__ W2, const float* __restrict__ b2,
    float* __restrict__ accum, int E)
{
    const int lane = threadIdx.x & 63;
    const int li   = lane & 15;
    const int gi   = lane >> 4;

    bf16x8 w1f[8][2];
#pragma unroll
    for (int t = 0; t < 8; ++t)
#pragma unroll
        for (int s = 0; s < 2; ++s)
#pragma unroll
            for (int j = 0; j < 8; ++j)
                w1f[t][s][j] = (short)f2bf(W1[(32 * s + gi * 8 + j) * H_DIM + 16 * t + li]);
    float b1r[8], w2r[8];
#pragma unroll
    for (int t = 0; t < 8; ++t) {
        b1r[t] = b1[16 * t + li];
        w2r[t] = W2[16 * t + li];
    }
    const float b2v = b2[0];

    const int wid = (blockIdx.x * blockDim.x + threadIdx.x) >> 6;
    const int nw  = (gridDim.x * blockDim.x) >> 6;
    const int NBpos = E >> 4;
    const int NB    = NBpos << 1;

    float lp = 0.f;
    for (int pb = wid; pb < NB; pb += nw) {
        const bool pos = pb < NBpos;
        const int pbase = (pos ? pb : pb - NBpos) << 4;
        const int* __restrict__ idx = pos ? eidx : nidx;
        const int u = idx[pbase + li];
        const int v = idx[E + pbase + li];

        const unsigned short* zu = zb + (size_t)u * D_LAT + gi * 8;
        const unsigned short* zv = zb + (size_t)v * D_LAT + gi * 8;
        const u16x8 a0 = *(const u16x8*)(zu);
        const u16x8 a1 = *(const u16x8*)(zu + 32);
        const u16x8 c0 = *(const u16x8*)(zv);
        const u16x8 c1 = *(const u16x8*)(zv + 32);

        bf16x8 pa0, pa1;
#pragma unroll
        for (int j = 0; j < 8; ++j) {
            pa0[j] = (short)f2bf(bf2f(a0[j]) * bf2f(c0[j]));
            pa1[j] = (short)f2bf(bf2f(a1[j]) * bf2f(c1[j]));
        }

        f32x4 acc[8];
#pragma unroll
        for (int t = 0; t < 8; ++t) acc[t] = (f32x4){0.f, 0.f, 0.f, 0.f};
#pragma unroll
        for (int t = 0; t < 8; ++t) {
            acc[t] = __builtin_amdgcn_mfma_f32_16x16x32_bf16(pa0, w1f[t][0], acc[t], 0, 0, 0);
            acc[t] = __builtin_amdgcn_mfma_f32_16x16x32_bf16(pa1, w1f[t][1], acc[t], 0, 0, 0);
        }

        float t0 = 0.f, t1 = 0.f, t2 = 0.f, t3 = 0.f;
#pragma unroll
        for (int t = 0; t < 8; ++t) {
            t0 += fmaxf(acc[t][0] + b1r[t], 0.f) * w2r[t];
            t1 += fmaxf(acc[t][1] + b1r[t], 0.f) * w2r[t];
            t2 += fmaxf(acc[t][2] + b1r[t], 0.f) * w2r[t];
            t3 += fmaxf(acc[t][3] + b1r[t], 0.f) * w2r[t];
        }
#pragma unroll
        for (int off = 1; off < 16; off <<= 1) {
            t0 += __shfl_xor(t0, off);
            t1 += __shfl_xor(t1, off);
            t2 += __shfl_xor(t2, off);
            t3 += __shfl_xor(t3, off);
        }
        const float sg = pos ? 1.f : -1.f;
        const float l0 = sg * (t0 + b2v), l1 = sg * (t1 + b2v);
        const float l2 = sg * (t2 + b2v), l3 = sg * (t3 + b2v);
        lp += fminf(l0, 0.f) - __logf(1.f + __expf(-fabsf(l0)));
        lp += fminf(l1, 0.f) - __logf(1.f + __expf(-fabsf(l1)));
        lp += fminf(l2, 0.f) - __logf(1.f + __expf(-fabsf(l2)));
        lp += fminf(l3, 0.f) - __logf(1.f + __expf(-fabsf(l3)));
    }
    for (int off = 32; off; off >>= 1) lp += __shfl_xor(lp, off);
    if (lane == 0) atomicAdd(&accum[0], lp * 0.0625f);
}

// ---------------- finalize ----------------
__global__ void fin_kernel(const float* __restrict__ accum, float* __restrict__ out,
                           int nNodes, int E)
{
    const float recon = accum[0] / (float)(2 * E);
    const float kl    = accum[1] / (float)nNodes;
    out[0] = kl - recon;
}

extern "C" void kernel_launch(void* const* d_in, const int* in_sizes, int n_in,
                              void* d_out, int out_size, void* d_ws, size_t ws_size,
                              hipStream_t stream)
{
    const float* x    = (const float*)d_in[0];
    const float* eps  = (const float*)d_in[1];
    const float* Wmu  = (const float*)d_in[2];
    const float* bmu  = (const float*)d_in[3];
    const float* Wlv  = (const float*)d_in[4];
    const float* blv  = (const float*)d_in[5];
    const float* W1   = (const float*)d_in[6];
    const float* b1   = (const float*)d_in[7];
    const float* W2   = (const float*)d_in[8];
    const float* b2   = (const float*)d_in[9];
    const int*   eidx = (const int*)d_in[10];
    const int*   nidx = (const int*)d_in[11];

    const int nNodes = in_sizes[1] / D_LAT;   // 100000
    const int E      = in_sizes[10] / 2;      // 1000000

    float* accum          = (float*)d_ws;
    unsigned short* zbf16 = (unsigned short*)((char*)d_ws + 256);

    hipMemsetAsync(d_ws, 0, 256, stream);
    enc_mfma_kernel<<<512, 256, 0, stream>>>(x, eps, Wmu, bmu, Wlv, blv, zbf16, accum, nNodes);
    edge_mfma_kernel<<<2048, 256, 0, stream>>>(zbf16, eidx, nidx, W1, b1, W2, b2, accum, E);
    fin_kernel<<<1, 1, 0, stream>>>(accum, (float*)d_out, nNodes, E);
}